// Round 1
// baseline (1291.157 us; speedup 1.0000x reference)
//
#include <hip/hip_runtime.h>
#include <hip/hip_bf16.h>

typedef __attribute__((ext_vector_type(8))) short bf16x8;
typedef __attribute__((ext_vector_type(4))) float f32x4;

#define MFMA16(a,b,c) __builtin_amdgcn_mfma_f32_16x16x32_bf16(a,b,c,0,0,0)

__device__ inline ushort f2bf(float f){
  union { float f; uint u; } v; v.f = f;
  uint r = v.u + 0x7FFFu + ((v.u >> 16) & 1u);
  return (ushort)(r >> 16);
}
__device__ inline float sigf(float x){ return 1.f/(1.f+__expf(-x)); }
__device__ inline float tanhf_(float x){ return 2.f/(1.f+__expf(-2.f*x)) - 1.f; }

__device__ inline void gload_lds16(const ushort* g, ushort* lds){
  __builtin_amdgcn_global_load_lds(
      (const __attribute__((address_space(1))) void*)g,
      (__attribute__((address_space(3))) void*)lds, 16, 0, 0);
}

// ---------------- weight fp32 -> bf16 conversion ----------------
// 4 tensors, each 2*2048*512 = 2097152 elems, packed consecutively in dst.
__global__ void convert_weights(const float* __restrict__ s0, const float* __restrict__ s1,
                                const float* __restrict__ s2, const float* __restrict__ s3,
                                ushort* __restrict__ dst){
  size_t i4 = ((size_t)blockIdx.x*256 + threadIdx.x)*4;
  int tsel = (int)(i4 >> 21);
  const float* s = (tsel & 2) ? ((tsel & 1) ? s3 : s2) : ((tsel & 1) ? s1 : s0);
  size_t off = i4 & 2097151u;
  float4 v = *(const float4*)&s[off];
  ushort4 o; o.x=f2bf(v.x); o.y=f2bf(v.y); o.z=f2bf(v.z); o.w=f2bf(v.w);
  *(ushort4*)&dst[i4] = o;
}

// ---------------- embed = ((obsVel-mean)/std) @ enc_W + enc_b  (bf16 out) ----------------
__global__ void embed_kernel(const float* __restrict__ obsVel, const float* __restrict__ mean,
                             const float* __restrict__ stdv, const float* __restrict__ encW,
                             const float* __restrict__ encb, ushort* __restrict__ embed){
  int idx = blockIdx.x*256 + threadIdx.x;   // < 32768*512
  int row = idx >> 9, col = idx & 511;
  float x0 = (obsVel[row*2+0] - mean[0]) / stdv[0];
  float x1 = (obsVel[row*2+1] - mean[1]) / stdv[1];
  float v = x0*encW[col] + x1*encW[512+col] + encb[col];
  embed[idx] = f2bf(v);
}

// ---------------- fused LSTM cell step ----------------
// g[m][n] = A0@B0^T (+ A1@B1^T) + bias ; gates -> c update, h out (bf16).
// Block: 256 thr (4 waves). Tile: BM=128 rows x (4 gates x GN=32 cols) = 128x128 of g.
// Wave w owns rows [32w,32w+32), all 4 gates. LDS A:128x32, B:128x32 bf16, XOR-4 swizzled
// via pre-swizzled global source (LDS dest linear for global_load_lds).
#define BM 128
#define GN 32
#define BK 32

__global__ __launch_bounds__(256, 1) void lstm_cell_kernel(
    const ushort* __restrict__ A0, int lda0,
    const ushort* __restrict__ A1, int lda1,
    const ushort* __restrict__ B0,
    const ushort* __restrict__ B1,
    const float*  __restrict__ bias,
    float* __restrict__ C,
    ushort* __restrict__ H0, int ldh0,
    ushort* __restrict__ H1, int ldh1,
    int nSeg)
{
  __shared__ ushort aL[BM*BK];
  __shared__ ushort bL[128*BK];
  const int tid = threadIdx.x;
  const int w = tid >> 6, lane = tid & 63;
  const int bm = blockIdx.y * BM;
  const int bn = blockIdx.x * GN;

  f32x4 acc[2][8];
  #pragma unroll
  for (int m=0;m<2;m++)
    #pragma unroll
    for (int n=0;n<8;n++) acc[m][n] = (f32x4)0.f;

  const int nkt = nSeg << 4;
  for (int kt=0; kt<nkt; ++kt) {
    const ushort* Aseg = (kt<16)? A0 : A1;
    const int lda      = (kt<16)? lda0 : lda1;
    const ushort* Bseg = (kt<16)? B0 : B1;
    const int k0 = (kt & 15) * BK;
    // stage (pre-swizzled global source, linear LDS dest)
    #pragma unroll
    for (int p=0;p<2;p++){
      int i = p*256 + tid;
      int r = i>>2, kc = i&3;
      int gc = kc ^ (r & 3);
      const ushort* ga = Aseg + (size_t)(bm + r)*lda + k0 + gc*8;
      gload_lds16(ga, &aL[(size_t)(p*256 + (tid & ~63))*8]);
      int q = r>>5, r2 = r&31;
      const ushort* gb = Bseg + (size_t)(q*512 + bn + r2)*512 + k0 + gc*8;
      gload_lds16(gb, &bL[(size_t)(p*256 + (tid & ~63))*8]);
    }
    __syncthreads();
    bf16x8 af[2], bfr[8];
    #pragma unroll
    for (int m=0;m<2;m++){
      int row = w*32 + m*16 + (lane&15);
      int koff = (((lane>>4) ^ (row & 3)) * 8);
      af[m] = *(const bf16x8*)&aL[row*BK + koff];
    }
    #pragma unroll
    for (int n=0;n<8;n++){
      int q = n>>1, cc = n&1;
      int row = q*32 + cc*16 + (lane&15);
      int koff = (((lane>>4) ^ (row & 3)) * 8);
      bfr[n] = *(const bf16x8*)&bL[row*BK + koff];
    }
    #pragma unroll
    for (int m=0;m<2;m++)
      #pragma unroll
      for (int n=0;n<8;n++)
        acc[m][n] = MFMA16(af[m], bfr[n], acc[m][n]);
    __syncthreads();
  }

  // epilogue: bias + gates, c update, h writes
  const int r0 = bm + w*32 + ((lane>>4)<<2);
  const int col = bn + (lane&15);
  #pragma unroll
  for (int cc=0;cc<2;cc++){
    const int ccol = col + cc*16;             // gate-local col in [0,512)
    const float bi = bias[ccol];
    const float bff = bias[512+ccol];
    const float bg = bias[1024+ccol];
    const float bo = bias[1536+ccol];
    #pragma unroll
    for (int m=0;m<2;m++){
      #pragma unroll
      for (int reg=0;reg<4;reg++){
        const int row = r0 + m*16 + reg;
        float gi = acc[m][0+cc][reg] + bi;
        float gf = acc[m][2+cc][reg] + bff;
        float gg = acc[m][4+cc][reg] + bg;
        float go = acc[m][6+cc][reg] + bo;
        size_t cidx = (size_t)row*512 + ccol;
        float cv = C[cidx];
        float cn = sigf(gf)*cv + sigf(gi)*tanhf_(gg);
        float hv = sigf(go)*tanhf_(cn);
        C[cidx] = cn;
        ushort hb = f2bf(hv);
        H0[(size_t)row*ldh0 + ccol] = hb;
        if (H1) H1[(size_t)row*ldh1 + ccol] = hb;
      }
    }
  }
}

// ---------------- projection + cumsum ----------------
__global__ void final_kernel(const ushort* __restrict__ pred, const float* __restrict__ decW,
                             const float* __restrict__ decb, const float* __restrict__ mean,
                             const float* __restrict__ stdv, const float* __restrict__ obs,
                             float* __restrict__ out){
  int w = threadIdx.x >> 6, lane = threadIdx.x & 63;
  int b = blockIdx.x*4 + w;
  float w0[8], w1[8];
  #pragma unroll
  for (int j=0;j<8;j++){
    int k = lane*8 + j;
    w0[j] = decW[k*2+0];
    w1[j] = decW[k*2+1];
  }
  float cum0 = 0.f, cum1 = 0.f;
  float m0 = mean[0], m1 = mean[1], sv0 = stdv[0], sv1 = stdv[1];
  float o0 = obs[(b*8+7)*2+0], o1 = obs[(b*8+7)*2+1];
  float db0 = decb[0], db1 = decb[1];
  for (int t=0;t<12;t++){
    const uint4 q = *(const uint4*)&pred[((size_t)b*12+t)*512 + lane*8];
    uint u[4] = {q.x,q.y,q.z,q.w};
    float s0=0.f, s1=0.f;
    #pragma unroll
    for (int p=0;p<4;p++){
      float lo = __uint_as_float(u[p]<<16);
      float hi = __uint_as_float(u[p]&0xffff0000u);
      s0 += lo*w0[2*p] + hi*w0[2*p+1];
      s1 += lo*w1[2*p] + hi*w1[2*p+1];
    }
    #pragma unroll
    for (int off=32; off>0; off>>=1){ s0 += __shfl_down(s0, off); s1 += __shfl_down(s1, off); }
    if (lane==0){
      cum0 += (s0+db0)*sv0 + m0;
      cum1 += (s1+db1)*sv1 + m1;
      out[((size_t)b*12+t)*2+0] = cum0 + o0;
      out[((size_t)b*12+t)*2+1] = cum1 + o1;
    }
  }
}

extern "C" void kernel_launch(void* const* d_in, const int* in_sizes, int n_in,
                              void* d_out, int out_size, void* d_ws, size_t ws_size,
                              hipStream_t stream) {
  const float* obs      = (const float*)d_in[0];
  const float* obsVel   = (const float*)d_in[1];
  const float* mean     = (const float*)d_in[2];
  const float* stdv     = (const float*)d_in[3];
  const float* encW     = (const float*)d_in[5];
  const float* encb     = (const float*)d_in[6];
  const float* decW     = (const float*)d_in[7];
  const float* decb     = (const float*)d_in[8];
  const float* lstm_Wih = (const float*)d_in[9];
  const float* lstm_Whh = (const float*)d_in[10];
  const float* lstm_b   = (const float*)d_in[11];
  const float* cell_Wih = (const float*)d_in[12];
  const float* cell_Whh = (const float*)d_in[13];
  const float* cell_b   = (const float*)d_in[14];

  char* ws = (char*)d_ws;
  ushort* wbf   = (ushort*)ws;                       // 16 MB: 4 tensors x 2097152 elems
  ushort* embed = (ushort*)(ws + (16ull<<20));       // 32 MB
  ushort* h0[2] = {(ushort*)(ws + (48ull<<20)), (ushort*)(ws + (52ull<<20))};
  ushort* h1[2] = {(ushort*)(ws + (56ull<<20)), (ushort*)(ws + (60ull<<20))};
  float*  c0    = (float*)(ws + (64ull<<20));        // 8 MB
  float*  c1    = (float*)(ws + (72ull<<20));        // 8 MB
  ushort* pred  = (ushort*)(ws + (80ull<<20));       // 48 MB (4096 x 12 x 512 bf16)

  ushort* w_lstm_ih = wbf;
  ushort* w_lstm_hh = wbf + 2097152;
  ushort* w_cell_ih = wbf + 4194304;
  ushort* w_cell_hh = wbf + 6291456;

  hipMemsetAsync(c0, 0, 8ull<<20, stream);
  hipMemsetAsync(c1, 0, 8ull<<20, stream);

  convert_weights<<<8192, 256, 0, stream>>>(lstm_Wih, lstm_Whh, cell_Wih, cell_Whh, wbf);
  embed_kernel<<<65536, 256, 0, stream>>>(obsVel, mean, stdv, encW, encb, embed);

  dim3 grid(16, 32);
  int cur0 = 0, cur1 = 0;
  // encoder: 8 timesteps x 2 layers
  for (int t=0;t<8;t++){
    int ns = (t==0) ? 1 : 2;
    lstm_cell_kernel<<<grid, 256, 0, stream>>>(embed + t*512, 4096, h0[cur0], 512,
        w_lstm_ih, w_lstm_hh, lstm_b, c0, h0[cur0^1], 512, (ushort*)nullptr, 0, ns);
    lstm_cell_kernel<<<grid, 256, 0, stream>>>(h0[cur0^1], 512, h1[cur1], 512,
        w_lstm_ih + 1048576, w_lstm_hh + 1048576, lstm_b + 2048, c1, h1[cur1^1], 512,
        (t==7) ? pred : (ushort*)nullptr, 6144, ns);
    cur0 ^= 1; cur1 ^= 1;
  }
  // decoder: 11 steps x 2 layers
  for (int s=1;s<12;s++){
    lstm_cell_kernel<<<grid, 256, 0, stream>>>(pred + (s-1)*512, 6144, h0[cur0], 512,
        w_cell_ih, w_cell_hh, cell_b, c0, h0[cur0^1], 512, (ushort*)nullptr, 0, 2);
    lstm_cell_kernel<<<grid, 256, 0, stream>>>(h0[cur0^1], 512, h1[cur1], 512,
        w_cell_ih + 1048576, w_cell_hh + 1048576, cell_b + 2048, c1, h1[cur1^1], 512,
        pred + s*512, 6144, 2);
    cur0 ^= 1; cur1 ^= 1;
  }
  final_kernel<<<1024, 256, 0, stream>>>(pred, decW, decb, mean, stdv, obs, (float*)d_out);
}

// Round 2
// 1167.697 us; speedup vs baseline: 1.1057x; 1.1057x over previous
//
#include <hip/hip_runtime.h>
#include <hip/hip_bf16.h>

typedef __attribute__((ext_vector_type(8))) short bf16x8;
typedef __attribute__((ext_vector_type(4))) float f32x4;

#define MFMA16(a,b,c) __builtin_amdgcn_mfma_f32_16x16x32_bf16(a,b,c,0,0,0)

__device__ inline ushort f2bf(float f){
  union { float f; uint u; } v; v.f = f;
  uint r = v.u + 0x7FFFu + ((v.u >> 16) & 1u);
  return (ushort)(r >> 16);
}
__device__ inline float sigf(float x){ return 1.f/(1.f+__expf(-x)); }
__device__ inline float tanhf_(float x){ return 2.f/(1.f+__expf(-2.f*x)) - 1.f; }

__device__ inline void gload_lds16(const ushort* g, ushort* lds){
  __builtin_amdgcn_global_load_lds(
      (const __attribute__((address_space(1))) void*)g,
      (__attribute__((address_space(3))) void*)lds, 16, 0, 0);
}

// ---------------- weight fp32 -> bf16 conversion ----------------
__global__ void convert_weights(const float* __restrict__ s0, const float* __restrict__ s1,
                                const float* __restrict__ s2, const float* __restrict__ s3,
                                ushort* __restrict__ dst){
  size_t i4 = ((size_t)blockIdx.x*256 + threadIdx.x)*4;
  int tsel = (int)(i4 >> 21);
  const float* s = (tsel & 2) ? ((tsel & 1) ? s3 : s2) : ((tsel & 1) ? s1 : s0);
  size_t off = i4 & 2097151u;
  float4 v = *(const float4*)&s[off];
  ushort4 o; o.x=f2bf(v.x); o.y=f2bf(v.y); o.z=f2bf(v.z); o.w=f2bf(v.w);
  *(ushort4*)&dst[i4] = o;
}

// ---------------- embed = ((obsVel-mean)/std) @ enc_W + enc_b  (bf16 out) ----------------
__global__ void embed_kernel(const float* __restrict__ obsVel, const float* __restrict__ mean,
                             const float* __restrict__ stdv, const float* __restrict__ encW,
                             const float* __restrict__ encb, ushort* __restrict__ embed){
  int idx = blockIdx.x*256 + threadIdx.x;   // < 32768*512
  int row = idx >> 9, col = idx & 511;
  float x0 = (obsVel[row*2+0] - mean[0]) / stdv[0];
  float x1 = (obsVel[row*2+1] - mean[1]) / stdv[1];
  float v = x0*encW[col] + x1*encW[512+col] + encb[col];
  embed[idx] = f2bf(v);
}

// ---------------- fused LSTM cell step (2-phase double-buffered) ----------------
// g[m][n] = A0@B0^T (+ A1@B1^T) + bias ; gates -> c update, h out (bf16).
// Block: 256 thr (4 waves). Tile: BM=128 rows x (4 gates x GN=32 cols).
// Pipeline: STAGE(kt+1) issued before compute(kt); ONE __syncthreads per iter
// (its vmcnt(0) drain lands ~compute-time after issue). C-tile + bias loads
// hoisted above the K-loop so their latency hides under the GEMM.
#define BM 128
#define GN 32
#define BK 32

__global__ __launch_bounds__(256, 2) void lstm_cell_kernel(
    const ushort* __restrict__ A0, int lda0,
    const ushort* __restrict__ A1, int lda1,
    const ushort* __restrict__ B0,
    const ushort* __restrict__ B1,
    const float*  __restrict__ bias,
    float* __restrict__ C,
    ushort* __restrict__ H0, int ldh0,
    ushort* __restrict__ H1, int ldh1,
    int nSeg)
{
  __shared__ ushort aL[2][BM*BK];
  __shared__ ushort bL[2][128*BK];
  const int tid = threadIdx.x;
  const int w = tid >> 6, lane = tid & 63;
  const int bm = blockIdx.y * BM;
  const int bn = blockIdx.x * GN;

  // ---- prefetch epilogue operands (latency hidden under GEMM) ----
  const int r0 = bm + w*32 + ((lane>>4)<<2);
  const int col = bn + (lane&15);
  float creg[2][2][4];
  float br[2][4];
  #pragma unroll
  for (int cc=0;cc<2;cc++){
    const int ccol = col + cc*16;
    br[cc][0] = bias[ccol];
    br[cc][1] = bias[512+ccol];
    br[cc][2] = bias[1024+ccol];
    br[cc][3] = bias[1536+ccol];
    #pragma unroll
    for (int m=0;m<2;m++)
      #pragma unroll
      for (int reg=0;reg<4;reg++)
        creg[cc][m][reg] = C[(size_t)(r0 + m*16 + reg)*512 + ccol];
  }

  f32x4 acc[2][8];
  #pragma unroll
  for (int m=0;m<2;m++)
    #pragma unroll
    for (int n=0;n<8;n++) acc[m][n] = (f32x4)0.f;

  const int nkt = nSeg << 4;

  // stage indices (loop-invariant parts)
  const int i0 = tid, i1 = 256 + tid;
  const int ra0 = i0>>2, kc0 = i0&3, ra1 = i1>>2, kc1 = i1&3;
  const int gc0 = kc0 ^ (ra0 & 3), gc1 = kc1 ^ (ra1 & 3);
  const int ldsb0 = (tid & ~63)*8, ldsb1 = (256 + (tid & ~63))*8;

  #define STAGE(buf, kt) do { \
    const ushort* Aseg = ((kt)<16)? A0 : A1; \
    const int lda      = ((kt)<16)? lda0 : lda1; \
    const ushort* Bseg = ((kt)<16)? B0 : B1; \
    const int k0 = ((kt) & 15) * BK; \
    gload_lds16(Aseg + (size_t)(bm + ra0)*lda + k0 + gc0*8, &aL[buf][ldsb0]); \
    gload_lds16(Bseg + (size_t)((ra0>>5)*512 + bn + (ra0&31))*512 + k0 + gc0*8, &bL[buf][ldsb0]); \
    gload_lds16(Aseg + (size_t)(bm + ra1)*lda + k0 + gc1*8, &aL[buf][ldsb1]); \
    gload_lds16(Bseg + (size_t)((ra1>>5)*512 + bn + (ra1&31))*512 + k0 + gc1*8, &bL[buf][ldsb1]); \
  } while(0)

  STAGE(0, 0);
  __syncthreads();

  for (int kt=0; kt<nkt; ++kt) {
    const int cur = kt & 1;
    if (kt+1 < nkt) STAGE(cur^1, kt+1);

    bf16x8 af[2], bfr[8];
    #pragma unroll
    for (int m=0;m<2;m++){
      int row = w*32 + m*16 + (lane&15);
      int koff = (((lane>>4) ^ (row & 3)) * 8);
      af[m] = *(const bf16x8*)&aL[cur][row*BK + koff];
    }
    #pragma unroll
    for (int n=0;n<8;n++){
      int q = n>>1, cc = n&1;
      int row = q*32 + cc*16 + (lane&15);
      int koff = (((lane>>4) ^ (row & 3)) * 8);
      bfr[n] = *(const bf16x8*)&bL[cur][row*BK + koff];
    }
    #pragma unroll
    for (int m=0;m<2;m++)
      #pragma unroll
      for (int n=0;n<8;n++)
        acc[m][n] = MFMA16(af[m], bfr[n], acc[m][n]);
    __syncthreads();   // drains vmcnt(0): next tile staged, issued ~compute-time ago
  }
  #undef STAGE

  // epilogue: bias + gates, c update, h writes
  #pragma unroll
  for (int cc=0;cc<2;cc++){
    const int ccol = col + cc*16;
    const float bi = br[cc][0], bff = br[cc][1], bg = br[cc][2], bo = br[cc][3];
    #pragma unroll
    for (int m=0;m<2;m++){
      #pragma unroll
      for (int reg=0;reg<4;reg++){
        const int row = r0 + m*16 + reg;
        float gi = acc[m][0+cc][reg] + bi;
        float gf = acc[m][2+cc][reg] + bff;
        float gg = acc[m][4+cc][reg] + bg;
        float go = acc[m][6+cc][reg] + bo;
        float cv = creg[cc][m][reg];
        float cn = sigf(gf)*cv + sigf(gi)*tanhf_(gg);
        float hv = sigf(go)*tanhf_(cn);
        C[(size_t)row*512 + ccol] = cn;
        ushort hb = f2bf(hv);
        H0[(size_t)row*ldh0 + ccol] = hb;
        if (H1) H1[(size_t)row*ldh1 + ccol] = hb;
      }
    }
  }
}

// ---------------- projection + cumsum ----------------
__global__ void final_kernel(const ushort* __restrict__ pred, const float* __restrict__ decW,
                             const float* __restrict__ decb, const float* __restrict__ mean,
                             const float* __restrict__ stdv, const float* __restrict__ obs,
                             float* __restrict__ out){
  int w = threadIdx.x >> 6, lane = threadIdx.x & 63;
  int b = blockIdx.x*4 + w;
  float w0[8], w1[8];
  #pragma unroll
  for (int j=0;j<8;j++){
    int k = lane*8 + j;
    w0[j] = decW[k*2+0];
    w1[j] = decW[k*2+1];
  }
  float cum0 = 0.f, cum1 = 0.f;
  float m0 = mean[0], m1 = mean[1], sv0 = stdv[0], sv1 = stdv[1];
  float o0 = obs[(b*8+7)*2+0], o1 = obs[(b*8+7)*2+1];
  float db0 = decb[0], db1 = decb[1];
  for (int t=0;t<12;t++){
    const uint4 q = *(const uint4*)&pred[((size_t)b*12+t)*512 + lane*8];
    uint u[4] = {q.x,q.y,q.z,q.w};
    float s0=0.f, s1=0.f;
    #pragma unroll
    for (int p=0;p<4;p++){
      float lo = __uint_as_float(u[p]<<16);
      float hi = __uint_as_float(u[p]&0xffff0000u);
      s0 += lo*w0[2*p] + hi*w0[2*p+1];
      s1 += lo*w1[2*p] + hi*w1[2*p+1];
    }
    #pragma unroll
    for (int off=32; off>0; off>>=1){ s0 += __shfl_down(s0, off); s1 += __shfl_down(s1, off); }
    if (lane==0){
      cum0 += (s0+db0)*sv0 + m0;
      cum1 += (s1+db1)*sv1 + m1;
      out[((size_t)b*12+t)*2+0] = cum0 + o0;
      out[((size_t)b*12+t)*2+1] = cum1 + o1;
    }
  }
}

extern "C" void kernel_launch(void* const* d_in, const int* in_sizes, int n_in,
                              void* d_out, int out_size, void* d_ws, size_t ws_size,
                              hipStream_t stream) {
  const float* obs      = (const float*)d_in[0];
  const float* obsVel   = (const float*)d_in[1];
  const float* mean     = (const float*)d_in[2];
  const float* stdv     = (const float*)d_in[3];
  const float* encW     = (const float*)d_in[5];
  const float* encb     = (const float*)d_in[6];
  const float* decW     = (const float*)d_in[7];
  const float* decb     = (const float*)d_in[8];
  const float* lstm_Wih = (const float*)d_in[9];
  const float* lstm_Whh = (const float*)d_in[10];
  const float* lstm_b   = (const float*)d_in[11];
  const float* cell_Wih = (const float*)d_in[12];
  const float* cell_Whh = (const float*)d_in[13];
  const float* cell_b   = (const float*)d_in[14];

  char* ws = (char*)d_ws;
  ushort* wbf   = (ushort*)ws;                       // 16 MB: 4 tensors x 2097152 elems
  ushort* embed = (ushort*)(ws + (16ull<<20));       // 32 MB
  ushort* h0[2] = {(ushort*)(ws + (48ull<<20)), (ushort*)(ws + (52ull<<20))};
  ushort* h1[2] = {(ushort*)(ws + (56ull<<20)), (ushort*)(ws + (60ull<<20))};
  float*  c0    = (float*)(ws + (64ull<<20));        // 8 MB
  float*  c1    = (float*)(ws + (72ull<<20));        // 8 MB
  ushort* pred  = (ushort*)(ws + (80ull<<20));       // 48 MB (4096 x 12 x 512 bf16)

  ushort* w_lstm_ih = wbf;
  ushort* w_lstm_hh = wbf + 2097152;
  ushort* w_cell_ih = wbf + 4194304;
  ushort* w_cell_hh = wbf + 6291456;

  hipMemsetAsync(c0, 0, 8ull<<20, stream);
  hipMemsetAsync(c1, 0, 8ull<<20, stream);

  convert_weights<<<8192, 256, 0, stream>>>(lstm_Wih, lstm_Whh, cell_Wih, cell_Whh, wbf);
  embed_kernel<<<65536, 256, 0, stream>>>(obsVel, mean, stdv, encW, encb, embed);

  dim3 grid(16, 32);
  int cur0 = 0, cur1 = 0;
  // encoder: 8 timesteps x 2 layers
  for (int t=0;t<8;t++){
    int ns = (t==0) ? 1 : 2;
    lstm_cell_kernel<<<grid, 256, 0, stream>>>(embed + t*512, 4096, h0[cur0], 512,
        w_lstm_ih, w_lstm_hh, lstm_b, c0, h0[cur0^1], 512, (ushort*)nullptr, 0, ns);
    lstm_cell_kernel<<<grid, 256, 0, stream>>>(h0[cur0^1], 512, h1[cur1], 512,
        w_lstm_ih + 1048576, w_lstm_hh + 1048576, lstm_b + 2048, c1, h1[cur1^1], 512,
        (t==7) ? pred : (ushort*)nullptr, 6144, ns);
    cur0 ^= 1; cur1 ^= 1;
  }
  // decoder: 11 steps x 2 layers
  for (int s=1;s<12;s++){
    lstm_cell_kernel<<<grid, 256, 0, stream>>>(pred + (s-1)*512, 6144, h0[cur0], 512,
        w_cell_ih, w_cell_hh, cell_b, c0, h0[cur0^1], 512, (ushort*)nullptr, 0, 2);
    lstm_cell_kernel<<<grid, 256, 0, stream>>>(h0[cur0^1], 512, h1[cur1], 512,
        w_cell_ih + 1048576, w_cell_hh + 1048576, cell_b + 2048, c1, h1[cur1^1], 512,
        pred + s*512, 6144, 2);
    cur0 ^= 1; cur1 ^= 1;
  }
  final_kernel<<<1024, 256, 0, stream>>>(pred, decW, decb, mean, stdv, obs, (float*)d_out);
}